// Round 4
// baseline (791.911 us; speedup 1.0000x reference)
//
#include <hip/hip_runtime.h>
#include <hip/hip_bf16.h>

#define KS 64   // number of tags/states == wavefront size
#define PF 3    // emission prefetch depth; (T-1)=1023 divisible by 3

// ---------------------------------------------------------------------------
// Kernel A: log-partition (forward algorithm), one 64-lane wave per batch.
// State carried in scaled-exp domain: w_j ~ exp(S_tj - M_t).
// Per-step applied scale s_t = exp(-pred_t) is a FREE uniform factor whose
// exact log is folded into M (bookkeeping exact for any pred). pred is a
// range-controlling prediction from the previous step's MEASURED raw0
// (shfl, off-chain) + known factors; per-step prediction error is bounded
// by the transition spread (±0.3) with no feedback -> stable.
// Critical chain: LDS broadcast reads -> 64 FMA -> fmul -> cndmask -> ds_write.
// ---------------------------------------------------------------------------
__global__ __launch_bounds__(64, 1) void crf_logZ_kernel(
    const float* __restrict__ em,          // [B, T, K]
    const int* __restrict__ mask,          // [B, T]  (bool -> int32)
    const float* __restrict__ trans,       // [K, K]
    const float* __restrict__ startT,      // [K]
    const float* __restrict__ endT,        // [K]
    float* __restrict__ logZ,              // [B]
    int T)
{
    const int b = blockIdx.x;
    const int j = threadIdx.x;   // 0..63, state index

    // Per-lane column of exp(transitions): Ecol[i] = exp(trans[i][j]).
    float Ecol[KS];
#pragma unroll
    for (int i = 0; i < KS; ++i)
        Ecol[i] = __expf(trans[i * KS + j]);

    const float* emb = em + (size_t)b * T * KS;
    const int*   mb  = mask + (size_t)b * T;

    // t = 0:  S_0j = start_j + em_0j;  M = S_00;  w = exp(S_0j - M)
    float em0 = emb[j];
    float s0  = startT[j] + em0;
    float M   = __shfl(s0, 0);
    float w   = __expf(s0 - M);

    __shared__ __align__(16) float p[KS];
    p[j] = w;
    __builtin_amdgcn_wave_barrier();

    // initial prediction of log raw_{1,0} ~ log(sum_j w_j)  (error <= 0.1)
    float sw = w;
#pragma unroll
    for (int off = 1; off < 64; off <<= 1) sw += __shfl_xor(sw, off);
    float pred = __logf(sw);

    // emission/mask prefetch registers (statically indexed via unroll)
    float em_pf[PF];
    int   mk_pf[PF];
#pragma unroll
    for (int k = 0; k < PF; ++k) {
        em_pf[k] = emb[(size_t)(1 + k) * KS + j];
        mk_pf[k] = mb[1 + k];
    }

    for (int t0 = 1; t0 < T; t0 += PF) {
#pragma unroll
        for (int u = 0; u < PF; ++u) {
            const int t = t0 + u;
            const float em_t = em_pf[u];
            const int   m_t  = mk_pf[u];
            const int   tn   = t + PF;
            if (tn < T) {                 // uniform; false only in last group
                em_pf[u] = emb[(size_t)tn * KS + j];
                mk_pf[u] = mb[tn];
            }

            // ---- off-chain prep (prefetched inputs, 1-3 steps of slack) ----
            const float e0 = __shfl(em_t, 0);
            const float g  = __expf(em_t - e0);      // per-lane emission factor
            float G = g;                              // sum_j g_j (butterfly)
#pragma unroll
            for (int off = 1; off < 64; off <<= 1) G += __shfl_xor(G, off);
            const float lG  = __logf(G);
            const float s_t = __expf(-pred);          // applied uniform scale
            const float f   = g * s_t;

            // ---- chain: raw_j = sum_i w_i * E_ij  (LDS broadcast reads) ----
            float a0 = 0.f, a1 = 0.f, a2 = 0.f, a3 = 0.f;
            float a4 = 0.f, a5 = 0.f, a6 = 0.f, a7 = 0.f;
#pragma unroll
            for (int c = 0; c < 16; ++c) {
                const float4 pq = *(const float4*)&p[c * 4];
                if (c & 1) {
                    a4 = fmaf(pq.x, Ecol[c * 4 + 0], a4);
                    a5 = fmaf(pq.y, Ecol[c * 4 + 1], a5);
                    a6 = fmaf(pq.z, Ecol[c * 4 + 2], a6);
                    a7 = fmaf(pq.w, Ecol[c * 4 + 3], a7);
                } else {
                    a0 = fmaf(pq.x, Ecol[c * 4 + 0], a0);
                    a1 = fmaf(pq.y, Ecol[c * 4 + 1], a1);
                    a2 = fmaf(pq.z, Ecol[c * 4 + 2], a2);
                    a3 = fmaf(pq.w, Ecol[c * 4 + 3], a3);
                }
            }
            const float raw = ((a0 + a4) + (a1 + a5)) + ((a2 + a6) + (a3 + a7));

            // ---- chain tail ----
            const float wn = f * raw;
            w = m_t ? wn : w;
            p[j] = w;                    // single buffer: in-wave DS ordering
            __builtin_amdgcn_wave_barrier();

            // ---- off-chain bookkeeping for next step ----
            const float q  = __shfl(raw, 0);   // measured raw0 (1-step slack)
            const float lq = __logf(q);
            M    = m_t ? (M + e0 + pred) : M;        // exact: log s_t == -pred
            pred = m_t ? (lq - pred + lG) : lq;      // range prediction only
        }
    }

    // logZ_b = M + log(sum_j w_j * exp(end_j))
    float val = w * __expf(endT[j]);
#pragma unroll
    for (int off = 1; off < 64; off <<= 1) val += __shfl_xor(val, off);
    if (j == 0) logZ[b] = M + __logf(val);
}

// ---------------------------------------------------------------------------
// Kernel B: gold path score, one block (256 thr) per batch, strided over T.
// ---------------------------------------------------------------------------
__global__ __launch_bounds__(256) void crf_gold_kernel(
    const float* __restrict__ em,          // [B, T, K]
    const int* __restrict__ tags,          // [B, T]
    const int* __restrict__ mask,          // [B, T]
    const float* __restrict__ trans,       // [K, K]
    const float* __restrict__ startT,      // [K]
    const float* __restrict__ endT,        // [K]
    float* __restrict__ gold,              // [B]
    int T)
{
    const int b = blockIdx.x;
    const int tid = threadIdx.x;

    const float* emb = em + (size_t)b * T * KS;
    const int* tb = tags + (size_t)b * T;
    const int* mb = mask + (size_t)b * T;

    float acc = 0.f;
    int cnt = 0;
    for (int t = tid; t < T; t += 256) {
        int tg = tb[t];
        int mv = mb[t];
        float mf = mv ? 1.f : 0.f;
        acc += emb[t * KS + tg] * mf;            // emission gather
        if (t >= 1) {
            int tgp = tb[t - 1];
            acc += trans[tgp * KS + tg] * mf;    // transition gather
        }
        cnt += mv ? 1 : 0;
    }

#pragma unroll
    for (int off = 32; off; off >>= 1) {
        acc += __shfl_xor(acc, off);
        cnt += __shfl_xor(cnt, off);
    }
    __shared__ float wacc[4];
    __shared__ int   wcnt[4];
    int wv = tid >> 6;
    if ((tid & 63) == 0) { wacc[wv] = acc; wcnt[wv] = cnt; }
    __syncthreads();
    if (tid == 0) {
        float a = wacc[0] + wacc[1] + wacc[2] + wacc[3];
        int   c = wcnt[0] + wcnt[1] + wcnt[2] + wcnt[3];
        int last = c - 1;                 // index of last valid timestep
        gold[b] = a + startT[tb[0]] + endT[tb[last]];
    }
}

// ---------------------------------------------------------------------------
// Kernel C: mean over batch of (logZ - gold) -> scalar output.
// ---------------------------------------------------------------------------
__global__ __launch_bounds__(512) void crf_reduce_kernel(
    const float* __restrict__ logZ,
    const float* __restrict__ gold,
    float* __restrict__ out, int B)
{
    int tid = threadIdx.x;
    float v = 0.f;
    for (int i = tid; i < B; i += 512) v += logZ[i] - gold[i];
#pragma unroll
    for (int off = 32; off; off >>= 1) v += __shfl_xor(v, off);
    __shared__ float ws[8];
    int w = tid >> 6;
    if ((tid & 63) == 0) ws[w] = v;
    __syncthreads();
    if (tid == 0) {
        float s = 0.f;
#pragma unroll
        for (int k = 0; k < 8; ++k) s += ws[k];
        out[0] = s / (float)B;
    }
}

// ---------------------------------------------------------------------------
extern "C" void kernel_launch(void* const* d_in, const int* in_sizes, int n_in,
                              void* d_out, int out_size, void* d_ws, size_t ws_size,
                              hipStream_t stream)
{
    const float* emissions = (const float*)d_in[0];
    const int*   tags      = (const int*)d_in[1];
    const int*   mask      = (const int*)d_in[2];
    const float* trans     = (const float*)d_in[3];
    const float* startT    = (const float*)d_in[4];
    const float* endT      = (const float*)d_in[5];

    const int T = 1024;                 // fixed by problem setup
    const int B = in_sizes[1] / T;      // in_sizes[1] = B*T

    float* logZ = (float*)d_ws;
    float* gold = logZ + B;

    crf_logZ_kernel<<<B, 64, 0, stream>>>(emissions, mask, trans, startT, endT, logZ, T);
    crf_gold_kernel<<<B, 256, 0, stream>>>(emissions, tags, mask, trans, startT, endT, gold, T);
    crf_reduce_kernel<<<1, 512, 0, stream>>>(logZ, gold, (float*)d_out, B);
}

// Round 5
// 691.179 us; speedup vs baseline: 1.1457x; 1.1457x over previous
//
#include <hip/hip_runtime.h>
#include <hip/hip_bf16.h>

#define KS 64   // number of tags/states == wavefront size
#define PF 4    // emission prefetch depth (steps of lookahead)

// ---------------------------------------------------------------------------
// Kernel A: log-partition (forward algorithm), one 64-lane wave per batch.
// Invariant: S_tj = M + log w_j.  Per step (exp domain):
//   raw_j = sum_i w_i * E_ij          (LDS broadcast + 64 reg FMA)
//   even step:  w' = (g*raw)*rcp(raw0),  M += e0 + log(raw0)
//   odd  step:  w' = g*raw,              M += e0            (no normalize)
// g = exp(em_t - e0) is computed from emissions prefetched PF steps ahead
// (off-chain). raw0 = current-step readlane -> rcp: stable, lane0 w == 1.
// log(raw0) is consumed only by M (read at the end) -> runs in next step's
// shadow. Single wave: no barriers, in-order DS pipe handles p RAW.
// ---------------------------------------------------------------------------
__global__ __launch_bounds__(64, 1) void crf_logZ_kernel(
    const float* __restrict__ em,          // [B, T, K]
    const int* __restrict__ mask,          // [B, T]  (bool -> int32)
    const float* __restrict__ trans,       // [K, K]
    const float* __restrict__ startT,      // [K]
    const float* __restrict__ endT,        // [K]
    float* __restrict__ logZ,              // [B]
    int T)
{
    const int b = blockIdx.x;
    const int j = threadIdx.x;   // 0..63, state index

    // Per-lane column of exp(transitions): Ecol[i] = exp(trans[i][j]).
    float Ecol[KS];
#pragma unroll
    for (int i = 0; i < KS; ++i)
        Ecol[i] = __expf(trans[i * KS + j]);

    const float* emb = em + (size_t)b * T * KS;
    const int*   mb  = mask + (size_t)b * T;

    // t = 0:  S_0j = start_j + em_0j;  M = S_00;  w = exp(S_0j - M); w0 = 1
    float em0 = emb[j];
    float s0  = startT[j] + em0;
    float M   = __shfl(s0, 0);
    float w   = __expf(s0 - M);

    __shared__ __align__(16) float p[KS];
    p[j] = w;
    __builtin_amdgcn_wave_barrier();

    // emission/mask prefetch registers (statically indexed via unroll)
    float em_pf[PF];
    int   mk_pf[PF];
#pragma unroll
    for (int k = 0; k < PF; ++k) {
        em_pf[k] = emb[(size_t)(1 + k) * KS + j];
        mk_pf[k] = mb[1 + k];
    }

    for (int t0 = 1; t0 < T; t0 += PF) {
#pragma unroll
        for (int u = 0; u < PF; ++u) {
            const int t = t0 + u;
            if (t < T) {                       // uniform; partial last group
                const float em_t = em_pf[u];
                const int   m_t  = mk_pf[u];
                const int   tn   = t + PF;
                if (tn < T) {                  // refill prefetch slot
                    em_pf[u] = emb[(size_t)tn * KS + j];
                    mk_pf[u] = mb[tn];
                }

                // off-chain: per-lane emission factor (inputs PF steps old)
                const float e0 = __shfl(em_t, 0);
                const float g  = __expf(em_t - e0);

                // chain: raw_j = sum_i w_i * E_ij (LDS broadcast reads)
                float a0 = 0.f, a1 = 0.f, a2 = 0.f, a3 = 0.f;
                float a4 = 0.f, a5 = 0.f, a6 = 0.f, a7 = 0.f;
#pragma unroll
                for (int c = 0; c < 16; ++c) {
                    const float4 pq = *(const float4*)&p[c * 4];
                    if (c & 1) {
                        a4 = fmaf(pq.x, Ecol[c * 4 + 0], a4);
                        a5 = fmaf(pq.y, Ecol[c * 4 + 1], a5);
                        a6 = fmaf(pq.z, Ecol[c * 4 + 2], a6);
                        a7 = fmaf(pq.w, Ecol[c * 4 + 3], a7);
                    } else {
                        a0 = fmaf(pq.x, Ecol[c * 4 + 0], a0);
                        a1 = fmaf(pq.y, Ecol[c * 4 + 1], a1);
                        a2 = fmaf(pq.z, Ecol[c * 4 + 2], a2);
                        a3 = fmaf(pq.w, Ecol[c * 4 + 3], a3);
                    }
                }
                const float raw =
                    ((a0 + a4) + (a1 + a5)) + ((a2 + a6) + (a3 + a7));

                float wn, Madd;
                if (u & 1) {
                    // normalize: w'0 == g0 == 1, unconditionally stable
                    const float r0  = __shfl(raw, 0);
                    const float inv = __builtin_amdgcn_rcpf(r0);
                    wn   = (g * raw) * inv;        // g*raw overlaps rcp
                    Madd = e0 + __logf(r0);        // consumed at end only
                } else {
                    wn   = g * raw;                // scale carried in w
                    Madd = e0;
                }
                w = m_t ? wn : w;
                M = m_t ? (M + Madd) : M;
                p[j] = w;                          // in-wave DS ordering
                __builtin_amdgcn_wave_barrier();
            }
        }
    }

    // logZ_b = M + log(sum_j w_j * exp(end_j))   (valid for any w scale)
    float val = w * __expf(endT[j]);
#pragma unroll
    for (int off = 1; off < 64; off <<= 1) val += __shfl_xor(val, off);
    if (j == 0) logZ[b] = M + __logf(val);
}

// ---------------------------------------------------------------------------
// Kernel B: gold path score, one block (256 thr) per batch, strided over T.
// ---------------------------------------------------------------------------
__global__ __launch_bounds__(256) void crf_gold_kernel(
    const float* __restrict__ em,          // [B, T, K]
    const int* __restrict__ tags,          // [B, T]
    const int* __restrict__ mask,          // [B, T]
    const float* __restrict__ trans,       // [K, K]
    const float* __restrict__ startT,      // [K]
    const float* __restrict__ endT,        // [K]
    float* __restrict__ gold,              // [B]
    int T)
{
    const int b = blockIdx.x;
    const int tid = threadIdx.x;

    const float* emb = em + (size_t)b * T * KS;
    const int* tb = tags + (size_t)b * T;
    const int* mb = mask + (size_t)b * T;

    float acc = 0.f;
    int cnt = 0;
    for (int t = tid; t < T; t += 256) {
        int tg = tb[t];
        int mv = mb[t];
        float mf = mv ? 1.f : 0.f;
        acc += emb[t * KS + tg] * mf;            // emission gather
        if (t >= 1) {
            int tgp = tb[t - 1];
            acc += trans[tgp * KS + tg] * mf;    // transition gather
        }
        cnt += mv ? 1 : 0;
    }

#pragma unroll
    for (int off = 32; off; off >>= 1) {
        acc += __shfl_xor(acc, off);
        cnt += __shfl_xor(cnt, off);
    }
    __shared__ float wacc[4];
    __shared__ int   wcnt[4];
    int wv = tid >> 6;
    if ((tid & 63) == 0) { wacc[wv] = acc; wcnt[wv] = cnt; }
    __syncthreads();
    if (tid == 0) {
        float a = wacc[0] + wacc[1] + wacc[2] + wacc[3];
        int   c = wcnt[0] + wcnt[1] + wcnt[2] + wcnt[3];
        int last = c - 1;                 // index of last valid timestep
        gold[b] = a + startT[tb[0]] + endT[tb[last]];
    }
}

// ---------------------------------------------------------------------------
// Kernel C: mean over batch of (logZ - gold) -> scalar output.
// ---------------------------------------------------------------------------
__global__ __launch_bounds__(512) void crf_reduce_kernel(
    const float* __restrict__ logZ,
    const float* __restrict__ gold,
    float* __restrict__ out, int B)
{
    int tid = threadIdx.x;
    float v = 0.f;
    for (int i = tid; i < B; i += 512) v += logZ[i] - gold[i];
#pragma unroll
    for (int off = 32; off; off >>= 1) v += __shfl_xor(v, off);
    __shared__ float ws[8];
    int w = tid >> 6;
    if ((tid & 63) == 0) ws[w] = v;
    __syncthreads();
    if (tid == 0) {
        float s = 0.f;
#pragma unroll
        for (int k = 0; k < 8; ++k) s += ws[k];
        out[0] = s / (float)B;
    }
}

// ---------------------------------------------------------------------------
extern "C" void kernel_launch(void* const* d_in, const int* in_sizes, int n_in,
                              void* d_out, int out_size, void* d_ws, size_t ws_size,
                              hipStream_t stream)
{
    const float* emissions = (const float*)d_in[0];
    const int*   tags      = (const int*)d_in[1];
    const int*   mask      = (const int*)d_in[2];
    const float* trans     = (const float*)d_in[3];
    const float* startT    = (const float*)d_in[4];
    const float* endT      = (const float*)d_in[5];

    const int T = 1024;                 // fixed by problem setup
    const int B = in_sizes[1] / T;      // in_sizes[1] = B*T

    float* logZ = (float*)d_ws;
    float* gold = logZ + B;

    crf_logZ_kernel<<<B, 64, 0, stream>>>(emissions, mask, trans, startT, endT, logZ, T);
    crf_gold_kernel<<<B, 256, 0, stream>>>(emissions, tags, mask, trans, startT, endT, gold, T);
    crf_reduce_kernel<<<1, 512, 0, stream>>>(logZ, gold, (float*)d_out, B);
}

// Round 6
// 443.657 us; speedup vs baseline: 1.7850x; 1.5579x over previous
//
#include <hip/hip_runtime.h>
#include <hip/hip_bf16.h>

#define TT 1024
#define KS 64

typedef __attribute__((ext_vector_type(8))) short bf16x8;
typedef __attribute__((ext_vector_type(4))) float f32x4;

__device__ __forceinline__ unsigned short f2bf(float x) {
    union { __hip_bfloat16 h; unsigned short s; } u;
    u.h = __float2bfloat16(x);
    return u.s;
}
__device__ __forceinline__ float bflo(unsigned u) {
    union { unsigned v; float f; } w; w.v = u << 16; return w.f;
}
__device__ __forceinline__ float bfhi(unsigned u) {
    union { unsigned v; float f; } w; w.v = u & 0xFFFF0000u; return w.f;
}
__device__ __forceinline__ float f4c(const float4& v, int i) {
    return i == 0 ? v.x : i == 1 ? v.y : i == 2 ? v.z : v.w;
}
__device__ __forceinline__ unsigned u4c(const uint4& v, int i) {
    return i == 0 ? v.x : i == 1 ? v.y : i == 2 ? v.z : v.w;
}

// ---------------------------------------------------------------------------
// Pre-pass: g = bf16(exp(emissions)), massively parallel, memory-bound.
// ---------------------------------------------------------------------------
__global__ __launch_bounds__(256) void crf_expem(
    const float* __restrict__ em, uint4* __restrict__ g, long long n8)
{
    long long i = (long long)blockIdx.x * blockDim.x + threadIdx.x;
    const long long stride = (long long)gridDim.x * blockDim.x;
    const float4* p = (const float4*)em;
    for (; i < n8; i += stride) {
        float4 a = p[i * 2], b = p[i * 2 + 1];
        uint4 o;
        o.x = (unsigned)f2bf(__expf(a.x)) | ((unsigned)f2bf(__expf(a.y)) << 16);
        o.y = (unsigned)f2bf(__expf(a.z)) | ((unsigned)f2bf(__expf(a.w)) << 16);
        o.z = (unsigned)f2bf(__expf(b.x)) | ((unsigned)f2bf(__expf(b.y)) << 16);
        o.w = (unsigned)f2bf(__expf(b.z)) | ((unsigned)f2bf(__expf(b.w)) << 16);
        g[i] = o;
    }
}

// ---------------------------------------------------------------------------
// Forward recursion via MFMA. One wave = 16 sequences.
//   lane l: c = l&15 (batch row / A-row), h = l>>4 (k-quarter)
//   A-frag (W, bf16): lane holds W[c][32*kk + 8*h + e], e=0..7, kk=0,1
//   B-frag (E, bf16): lane holds E[32*kk + 8*h + e][16*n + c], tiles n=0..3
//   D (f32x4):        lane holds raw[4*h + r][16*n + c], r=0..3
// Repack D->A through LDS [16][69] f32 (<=2-way banks both directions).
// Per step: w' = raw * g * rcp(raw[b][0]);  M[b] += log(raw[b][0]).
// Exact for any normalizer; no feedback -> stable. Single wave: no barriers.
// ---------------------------------------------------------------------------
template<bool PRE>
__global__ __launch_bounds__(64, 1) void crf_logZ_mfma(
    const float* __restrict__ em,
    const uint4* __restrict__ g4,        // bf16 exp(em), 8 values per uint4
    const int* __restrict__ mask,
    const float* __restrict__ trans,
    const float* __restrict__ startT,
    const float* __restrict__ endT,
    float* __restrict__ logZ)
{
    const int l = threadIdx.x;
    const int c = l & 15;
    const int h = l >> 4;
    const long long b = (long long)blockIdx.x * 16 + c;

    __shared__ float lds[16 * 69];

    // constant transition fragments (B-operand)
    bf16x8 E[4][2];
#pragma unroll
    for (int n = 0; n < 4; ++n)
#pragma unroll
        for (int kk = 0; kk < 2; ++kk) {
            union { unsigned short s[8]; bf16x8 v; } u;
#pragma unroll
            for (int e = 0; e < 8; ++e)
                u.s[e] = f2bf(__expf(trans[(32 * kk + 8 * h + e) * KS + 16 * n + c]));
            E[n][kk] = u.v;
        }

    float endE[2][8];
#pragma unroll
    for (int kk = 0; kk < 2; ++kk)
#pragma unroll
        for (int e = 0; e < 8; ++e)
            endE[kk][e] = __expf(endT[32 * kk + 8 * h + e]);

    const long long embase = b * (long long)TT * KS;  // element offset of row
    const long long g4base = embase / 8;
    const long long epbase = embase / 4;
    const int* mrow = mask + b * TT;
    const float4* ep = (const float4*)em;

    // ---- state init at t = 0:  w = exp(start_j + em0_j), M = 0 ----
    float w[2][8];
    if (PRE) {
#pragma unroll
        for (int kk = 0; kk < 2; ++kk) {
            uint4 v = g4[g4base + 4 * kk + h];
#pragma unroll
            for (int e = 0; e < 8; ++e) {
                unsigned uu = u4c(v, e >> 1);
                float gf = (e & 1) ? bfhi(uu) : bflo(uu);
                w[kk][e] = gf * __expf(startT[32 * kk + 8 * h + e]);
            }
        }
    } else {
        const float* erow = em + embase;
#pragma unroll
        for (int kk = 0; kk < 2; ++kk)
#pragma unroll
            for (int e = 0; e < 8; ++e) {
                int j = 32 * kk + 8 * h + e;
                w[kk][e] = __expf(erow[j] + startT[j]);
            }
    }
    float M = 0.f;

    bf16x8 af0, af1;
    {
        union { unsigned short s[8]; bf16x8 v; } p0, p1;
#pragma unroll
        for (int e = 0; e < 8; ++e) { p0.s[e] = f2bf(w[0][e]); p1.s[e] = f2bf(w[1][e]); }
        af0 = p0.v; af1 = p1.v;
    }

    // ---- prefetch buffers, 3 deep (1023 = 3*341 exactly) ----
    uint4  gb[3][2];
    float4 eb[3][4];
    int    mb[3];
#pragma unroll
    for (int s = 0; s < 3; ++s) {
        const int t = 1 + s;
        if (PRE) {
            gb[s][0] = g4[g4base + (long long)t * 8 + h];
            gb[s][1] = g4[g4base + (long long)t * 8 + 4 + h];
        } else {
            eb[s][0] = ep[epbase + (long long)t * 16 + 2 * h];
            eb[s][1] = ep[epbase + (long long)t * 16 + 2 * h + 1];
            eb[s][2] = ep[epbase + (long long)t * 16 + 8 + 2 * h];
            eb[s][3] = ep[epbase + (long long)t * 16 + 8 + 2 * h + 1];
        }
        mb[s] = mrow[t];
    }

    const int wrb = (4 * h) * 69 + c;
    const int rdb = c * 69 + 8 * h;

#define CRF_STEP(t, s) do {                                                    \
    const f32x4 z = {0.f, 0.f, 0.f, 0.f};                                      \
    f32x4 a0 = __builtin_amdgcn_mfma_f32_16x16x32_bf16(af0, E[0][0], z, 0,0,0);\
    f32x4 a1 = __builtin_amdgcn_mfma_f32_16x16x32_bf16(af0, E[1][0], z, 0,0,0);\
    f32x4 a2 = __builtin_amdgcn_mfma_f32_16x16x32_bf16(af0, E[2][0], z, 0,0,0);\
    f32x4 a3 = __builtin_amdgcn_mfma_f32_16x16x32_bf16(af0, E[3][0], z, 0,0,0);\
    a0 = __builtin_amdgcn_mfma_f32_16x16x32_bf16(af1, E[0][1], a0, 0,0,0);     \
    a1 = __builtin_amdgcn_mfma_f32_16x16x32_bf16(af1, E[1][1], a1, 0,0,0);     \
    a2 = __builtin_amdgcn_mfma_f32_16x16x32_bf16(af1, E[2][1], a2, 0,0,0);     \
    a3 = __builtin_amdgcn_mfma_f32_16x16x32_bf16(af1, E[3][1], a3, 0,0,0);     \
    lds[wrb +  0] = a0.x; lds[wrb +  0 + 69] = a0.y;                           \
    lds[wrb +  0 + 138] = a0.z; lds[wrb +  0 + 207] = a0.w;                    \
    lds[wrb + 16] = a1.x; lds[wrb + 16 + 69] = a1.y;                           \
    lds[wrb + 16 + 138] = a1.z; lds[wrb + 16 + 207] = a1.w;                    \
    lds[wrb + 32] = a2.x; lds[wrb + 32 + 69] = a2.y;                           \
    lds[wrb + 32 + 138] = a2.z; lds[wrb + 32 + 207] = a2.w;                    \
    lds[wrb + 48] = a3.x; lds[wrb + 48 + 69] = a3.y;                           \
    lds[wrb + 48 + 138] = a3.z; lds[wrb + 48 + 207] = a3.w;                    \
    const float r0 = lds[c * 69];                                              \
    float rw[2][8];                                                            \
    _Pragma("unroll") for (int kk2 = 0; kk2 < 2; ++kk2)                        \
    _Pragma("unroll") for (int e2 = 0; e2 < 8; ++e2)                           \
        rw[kk2][e2] = lds[rdb + 32 * kk2 + e2];                                \
    const float inv = __builtin_amdgcn_rcpf(r0);                               \
    const float lr  = __logf(r0);                                              \
    float gf[2][8];                                                            \
    if (PRE) {                                                                 \
        _Pragma("unroll") for (int kk2 = 0; kk2 < 2; ++kk2) {                  \
            const uint4 vv = gb[s][kk2];                                       \
            _Pragma("unroll") for (int e2 = 0; e2 < 8; ++e2) {                 \
                const unsigned uu = u4c(vv, e2 >> 1);                          \
                gf[kk2][e2] = (e2 & 1) ? bfhi(uu) : bflo(uu);                  \
            }                                                                  \
        }                                                                      \
    } else {                                                                   \
        _Pragma("unroll") for (int kk2 = 0; kk2 < 2; ++kk2)                    \
        _Pragma("unroll") for (int e2 = 0; e2 < 8; ++e2)                       \
            gf[kk2][e2] = __expf(f4c(eb[s][2 * kk2 + (e2 >> 2)], e2 & 3));     \
    }                                                                          \
    const unsigned long long bal = __ballot(mb[s] != 0);                       \
    if (bal == ~0ULL) {                                                        \
        _Pragma("unroll") for (int kk2 = 0; kk2 < 2; ++kk2)                    \
        _Pragma("unroll") for (int e2 = 0; e2 < 8; ++e2)                       \
            w[kk2][e2] = rw[kk2][e2] * (gf[kk2][e2] * inv);                    \
        M += lr;                                                               \
    } else {                                                                   \
        const bool mv = mb[s] != 0;                                            \
        _Pragma("unroll") for (int kk2 = 0; kk2 < 2; ++kk2)                    \
        _Pragma("unroll") for (int e2 = 0; e2 < 8; ++e2) {                     \
            const float wn = rw[kk2][e2] * (gf[kk2][e2] * inv);                \
            w[kk2][e2] = mv ? wn : w[kk2][e2];                                 \
        }                                                                      \
        M = mv ? (M + lr) : M;                                                 \
    }                                                                          \
    {                                                                          \
        union { unsigned short s8[8]; bf16x8 v; } q0, q1;                      \
        _Pragma("unroll") for (int e2 = 0; e2 < 8; ++e2) {                     \
            q0.s8[e2] = f2bf(w[0][e2]); q1.s8[e2] = f2bf(w[1][e2]);            \
        }                                                                      \
        af0 = q0.v; af1 = q1.v;                                                \
    }                                                                          \
    if ((t) + 3 < TT) {                                                        \
        if (PRE) {                                                             \
            gb[s][0] = g4[g4base + (long long)((t) + 3) * 8 + h];              \
            gb[s][1] = g4[g4base + (long long)((t) + 3) * 8 + 4 + h];          \
        } else {                                                               \
            eb[s][0] = ep[epbase + (long long)((t) + 3) * 16 + 2 * h];         \
            eb[s][1] = ep[epbase + (long long)((t) + 3) * 16 + 2 * h + 1];     \
            eb[s][2] = ep[epbase + (long long)((t) + 3) * 16 + 8 + 2 * h];     \
            eb[s][3] = ep[epbase + (long long)((t) + 3) * 16 + 8 + 2 * h + 1]; \
        }                                                                      \
        mb[s] = mrow[(t) + 3];                                                 \
    }                                                                          \
    __builtin_amdgcn_wave_barrier();                                           \
} while (0)

    for (int t0 = 1; t0 < TT; t0 += 3) {
        CRF_STEP(t0    , 0);
        CRF_STEP(t0 + 1, 1);
        CRF_STEP(t0 + 2, 2);
    }
#undef CRF_STEP

    // logZ_b = M + log(sum_j w_j * exp(end_j))
    float val = 0.f;
#pragma unroll
    for (int kk = 0; kk < 2; ++kk)
#pragma unroll
        for (int e = 0; e < 8; ++e)
            val += w[kk][e] * endE[kk][e];
    val += __shfl_xor(val, 16);
    val += __shfl_xor(val, 32);
    if (l < 16) logZ[(long long)blockIdx.x * 16 + l] = M + __logf(val);
}

// ---------------------------------------------------------------------------
// Gold path score, one block (256 thr) per batch, strided over T.
// ---------------------------------------------------------------------------
__global__ __launch_bounds__(256) void crf_gold_kernel(
    const float* __restrict__ em, const int* __restrict__ tags,
    const int* __restrict__ mask, const float* __restrict__ trans,
    const float* __restrict__ startT, const float* __restrict__ endT,
    float* __restrict__ gold, int T)
{
    const int b = blockIdx.x;
    const int tid = threadIdx.x;
    const float* emb = em + (size_t)b * T * KS;
    const int* tb = tags + (size_t)b * T;
    const int* mb = mask + (size_t)b * T;

    float acc = 0.f;
    int cnt = 0;
    for (int t = tid; t < T; t += 256) {
        int tg = tb[t];
        int mv = mb[t];
        float mf = mv ? 1.f : 0.f;
        acc += emb[t * KS + tg] * mf;
        if (t >= 1) acc += trans[tb[t - 1] * KS + tg] * mf;
        cnt += mv ? 1 : 0;
    }
#pragma unroll
    for (int off = 32; off; off >>= 1) {
        acc += __shfl_xor(acc, off);
        cnt += __shfl_xor(cnt, off);
    }
    __shared__ float wacc[4];
    __shared__ int   wcnt[4];
    int wv = tid >> 6;
    if ((tid & 63) == 0) { wacc[wv] = acc; wcnt[wv] = cnt; }
    __syncthreads();
    if (tid == 0) {
        float a = wacc[0] + wacc[1] + wacc[2] + wacc[3];
        int   cc = wcnt[0] + wcnt[1] + wcnt[2] + wcnt[3];
        gold[b] = a + startT[tb[0]] + endT[tb[cc - 1]];
    }
}

// ---------------------------------------------------------------------------
// mean(logZ - gold) -> scalar
// ---------------------------------------------------------------------------
__global__ __launch_bounds__(512) void crf_reduce_kernel(
    const float* __restrict__ logZ, const float* __restrict__ gold,
    float* __restrict__ out, int B)
{
    int tid = threadIdx.x;
    float v = 0.f;
    for (int i = tid; i < B; i += 512) v += logZ[i] - gold[i];
#pragma unroll
    for (int off = 32; off; off >>= 1) v += __shfl_xor(v, off);
    __shared__ float ws[8];
    int w = tid >> 6;
    if ((tid & 63) == 0) ws[w] = v;
    __syncthreads();
    if (tid == 0) {
        float s = 0.f;
#pragma unroll
        for (int k = 0; k < 8; ++k) s += ws[k];
        out[0] = s / (float)B;
    }
}

// ---------------------------------------------------------------------------
extern "C" void kernel_launch(void* const* d_in, const int* in_sizes, int n_in,
                              void* d_out, int out_size, void* d_ws, size_t ws_size,
                              hipStream_t stream)
{
    const float* emissions = (const float*)d_in[0];
    const int*   tags      = (const int*)d_in[1];
    const int*   mask      = (const int*)d_in[2];
    const float* trans     = (const float*)d_in[3];
    const float* startT    = (const float*)d_in[4];
    const float* endT      = (const float*)d_in[5];

    const int T = TT;
    const int B = in_sizes[1] / T;

    float* logZ = (float*)d_ws;
    float* gold = logZ + B;

    const size_t gbytes = (size_t)B * T * KS * 2;
    const bool pre = (ws_size >= 4096 + gbytes) && (B % 16 == 0);

    if (pre) {
        uint4* g = (uint4*)((char*)d_ws + 4096);
        long long n8 = (long long)B * T * KS / 8;
        crf_expem<<<4096, 256, 0, stream>>>(emissions, g, n8);
        crf_logZ_mfma<true><<<B / 16, 64, 0, stream>>>(
            emissions, (const uint4*)g, mask, trans, startT, endT, logZ);
    } else {
        crf_logZ_mfma<false><<<B / 16, 64, 0, stream>>>(
            emissions, nullptr, mask, trans, startT, endT, logZ);
    }
    crf_gold_kernel<<<B, 256, 0, stream>>>(emissions, tags, mask, trans, startT, endT, gold, T);
    crf_reduce_kernel<<<1, 512, 0, stream>>>(logZ, gold, (float*)d_out, B);
}